// Round 16
// baseline (99.887 us; speedup 1.0000x reference)
//
#include <hip/hip_runtime.h>
#include <hip/hip_bf16.h>

#define B_NUM 2
#define T_LEN 2048
#define D_DIM 1024
#define H_NUM 16
#define HD_DIM 64

// softmax scale folded into Q projection: 1/sqrt(64) * log2(e)
#define Q_PRESCALE 0.18033688011112042f

using bf16x8 = __attribute__((ext_vector_type(8))) short;
using f32x4  = __attribute__((ext_vector_type(4))) float;
using u16x4  = __attribute__((ext_vector_type(4))) unsigned short;

__device__ __forceinline__ unsigned short f2bf(float f) {
    union { __hip_bfloat16 b; unsigned short u; } v;
    v.b = __float2bfloat16(f);
    return v.u;
}

__device__ __forceinline__ unsigned pack2bf(float a, float b) {
    union { __hip_bfloat162 h; unsigned u; } v;
    v.h = __float22bfloat162_rn(float2{a, b});
    return v.u;
}

__device__ __forceinline__ void gload16(const unsigned short* g, unsigned short* l) {
    __builtin_amdgcn_global_load_lds(
        (const __attribute__((address_space(1))) void*)g,
        (__attribute__((address_space(3))) void*)l, 16, 0, 0);
}

// ---------------- convert fp32 -> bf16 (x + 4 weights), grid-stride ----------------
__global__ __launch_bounds__(256) void cvt5(
    const float* __restrict__ s0, const float* __restrict__ s1, const float* __restrict__ s2,
    const float* __restrict__ s3, const float* __restrict__ s4,
    unsigned short* __restrict__ d0, unsigned short* __restrict__ d1, unsigned short* __restrict__ d2,
    unsigned short* __restrict__ d3, unsigned short* __restrict__ d4,
    int c0, int c1, int c2, int c3, int c4)
{
    const float* src; unsigned short* dst; int cnt;
    switch (blockIdx.z) {
        case 0: src = s0; dst = d0; cnt = c0; break;
        case 1: src = s1; dst = d1; cnt = c1; break;
        case 2: src = s2; dst = d2; cnt = c2; break;
        case 3: src = s3; dst = d3; cnt = c3; break;
        default: src = s4; dst = d4; cnt = c4; break;
    }
    const int stride = gridDim.x * 256 * 4;
    for (int i = (blockIdx.x * 256 + threadIdx.x) * 4; i < cnt; i += stride) {
        float4 v = *(const float4*)(src + i);
        u16x4 o = { f2bf(v.x), f2bf(v.y), f2bf(v.z), f2bf(v.w) };
        *(u16x4*)(dst + i) = o;
    }
}

// ---------- 128x128 tile core: 3-buffer pipeline, counted vmcnt, fixed swizzle ----------
__device__ __forceinline__ void tile128(
    const unsigned short* __restrict__ A, const unsigned short* __restrict__ Bm,
    int m0, int n0, int K, unsigned short* lds, f32x4 acc[4][4])
{
    const int tid  = threadIdx.x;
    const int lane = tid & 63, w = tid >> 6;
    const int g = lane >> 4, c = lane & 15;
    const int wr = w >> 1, wc = w & 1;
    const int srow = lane >> 2;                 // row within 16-row staging chunk
    const int sch  = lane & 3;                  // 16B chunk within the 64B row
    const int scsw = sch ^ ((srow >> 1) & 3);   // swizzled source chunk
    const int chunk = w * 2;                    // wave stages chunks {chunk, chunk+1}
    const int row0 = chunk * 16 + srow;
    const int row1 = row0 + 16;
    const int rsw = (c >> 1) & 3;               // read-side XOR (row bits 1..2)

    #pragma unroll
    for (int mi = 0; mi < 4; ++mi)
        #pragma unroll
        for (int ni = 0; ni < 4; ++ni)
            acc[mi][ni] = (f32x4){0.f, 0.f, 0.f, 0.f};

    const unsigned short* gA0 = A  + (size_t)(m0 + row0) * K + scsw * 8;
    const unsigned short* gA1 = A  + (size_t)(m0 + row1) * K + scsw * 8;
    const unsigned short* gB0 = Bm + (size_t)(n0 + row0) * K + scsw * 8;
    const unsigned short* gB1 = Bm + (size_t)(n0 + row1) * K + scsw * 8;

    auto stage = [&](int buf, int k0) {
        unsigned short* bA = lds + buf * 8192;
        unsigned short* bB = bA + 4096;
        gload16(gA0 + k0, bA + chunk * 512);
        gload16(gA1 + k0, bA + (chunk + 1) * 512);
        gload16(gB0 + k0, bB + chunk * 512);
        gload16(gB1 + k0, bB + (chunk + 1) * 512);
    };

    auto kstep = [&](int buf) {
        __builtin_amdgcn_s_barrier();
        asm volatile("" ::: "memory");
        const unsigned short* bA = lds + buf * 8192;
        const unsigned short* bB = bA + 4096;
        bf16x8 af[4], bfr[4];
        #pragma unroll
        for (int mi = 0; mi < 4; ++mi)
            af[mi] = *(const bf16x8*)(bA + (wr * 64 + mi * 16 + c) * 32 + (g ^ rsw) * 8);
        #pragma unroll
        for (int ni = 0; ni < 4; ++ni)
            bfr[ni] = *(const bf16x8*)(bB + (wc * 64 + ni * 16 + c) * 32 + (g ^ rsw) * 8);
        #pragma unroll
        for (int mi = 0; mi < 4; ++mi)
            #pragma unroll
            for (int ni = 0; ni < 4; ++ni)
                acc[mi][ni] = __builtin_amdgcn_mfma_f32_16x16x32_bf16(af[mi], bfr[ni], acc[mi][ni], 0, 0, 0);
        asm volatile("s_waitcnt lgkmcnt(0)" ::: "memory");
        __builtin_amdgcn_s_barrier();
    };

    const int nsteps = K / 32;
    stage(0, 0);
    stage(1, 32);
    int buf = 0;
    #pragma unroll 1
    for (int t = 0; t + 2 < nsteps; ++t) {
        int nb = buf + 2; if (nb >= 3) nb -= 3;
        stage(nb, (t + 2) * 32);
        asm volatile("s_waitcnt vmcnt(8)" ::: "memory");
        kstep(buf);
        ++buf; if (buf == 3) buf = 0;
    }
    asm volatile("s_waitcnt vmcnt(4)" ::: "memory");
    kstep(buf);
    ++buf; if (buf == 3) buf = 0;
    asm volatile("s_waitcnt vmcnt(0)" ::: "memory");
    kstep(buf);
}

// Fused QKV projection, 1D grid of 768. XCD factorization 8mt x 12rr.
// Q output pre-scaled by Q_PRESCALE (softmax scale folded in, exp2 domain).
__global__ __launch_bounds__(256) void gemm_qkv(
    const unsigned short* __restrict__ X,
    const unsigned short* __restrict__ Wq, const unsigned short* __restrict__ Wk,
    const unsigned short* __restrict__ Wv,
    const float* __restrict__ bq, const float* __restrict__ bk, const float* __restrict__ bv,
    unsigned short* __restrict__ Oq, unsigned short* __restrict__ Ok, unsigned short* __restrict__ OvT)
{
    __shared__ __align__(16) unsigned short lds[3 * 8192];
    const int xcd = blockIdx.x & 7;
    const int s   = blockIdx.x >> 3;            // 0..95
    const int mt  = (xcd >> 1) * 8 + s / 12;
    const int rr  = (xcd & 1) * 12 + s % 12;
    const int z   = rr >> 3;
    const int nt  = rr & 7;

    const int lane = threadIdx.x & 63, w = threadIdx.x >> 6;
    const int g = lane >> 4, c = lane & 15;
    const int wr = w >> 1, wc = w & 1;
    f32x4 acc[4][4];

    if (z < 2) {
        const unsigned short* W = z ? Wk : Wq;
        const float* bias       = z ? bk : bq;
        unsigned short* Ob      = z ? Ok : Oq;
        const float oscale      = z ? 1.0f : Q_PRESCALE;
        const int m0 = mt * 128, n0 = nt * 128;
        tile128(X, W, m0, n0, D_DIM, lds, acc);
        #pragma unroll
        for (int mi = 0; mi < 4; ++mi) {
            #pragma unroll
            for (int ni = 0; ni < 4; ++ni) {
                const int col = n0 + wc * 64 + ni * 16 + c;
                const int h = col >> 6, hd = col & 63;
                const float bb = bias[col];
                #pragma unroll
                for (int r = 0; r < 4; ++r) {
                    const int row = m0 + wr * 64 + mi * 16 + g * 4 + r;
                    const int b_ = row >> 11, t = row & (T_LEN - 1);
                    Ob[((size_t)((b_ * H_NUM + h) * T_LEN + t)) * HD_DIM + hd] =
                        f2bf((acc[mi][ni][r] + bb) * oscale);
                }
            }
        }
    } else {
        // V^T: C'[f][j] = sum_k Wv[f][k] * X[j][k]
        const int m0 = nt * 128, n0 = mt * 128;
        tile128(Wv, X, m0, n0, D_DIM, lds, acc);
        #pragma unroll
        for (int mi = 0; mi < 4; ++mi) {
            #pragma unroll
            for (int ni = 0; ni < 4; ++ni) {
                const int j = n0 + wc * 64 + ni * 16 + c;
                const int b_ = j >> 11, t = j & (T_LEN - 1);
                #pragma unroll
                for (int r = 0; r < 4; ++r) {
                    const int f = m0 + wr * 64 + mi * 16 + g * 4 + r;
                    OvT[(size_t)(b_ * D_DIM + f) * T_LEN + t] = f2bf(acc[mi][ni][r] + bv[f]);
                }
            }
        }
    }
}

// Output projection: fp32 result to d_out. 256 blocks, XCD-chunked.
__global__ __launch_bounds__(256) void gemm_out(
    const unsigned short* __restrict__ A, const unsigned short* __restrict__ W,
    const float* __restrict__ bias, float* __restrict__ Out)
{
    __shared__ __align__(16) unsigned short lds[3 * 8192];
    const int bsw = (blockIdx.x & 7) * 32 + (blockIdx.x >> 3);
    const int mt = bsw >> 3, nt = bsw & 7;
    const int lane = threadIdx.x & 63, w = threadIdx.x >> 6;
    const int g = lane >> 4, c = lane & 15;
    const int m0 = mt * 128, n0 = nt * 128;
    f32x4 acc[4][4];
    tile128(A, W, m0, n0, D_DIM, lds, acc);
    const int wr = w >> 1, wc = w & 1;
    #pragma unroll
    for (int mi = 0; mi < 4; ++mi) {
        #pragma unroll
        for (int ni = 0; ni < 4; ++ni) {
            const int col = n0 + wc * 64 + ni * 16 + c;
            const float bb = bias[col];
            #pragma unroll
            for (int r = 0; r < 4; ++r) {
                const int row = m0 + wr * 64 + mi * 16 + g * 4 + r;
                Out[(size_t)row * D_DIM + col] = acc[mi][ni][r] + bb;
            }
        }
    }
}

// ---------------- flash attention v11: r10 structure + deferred-PV pipeline ----------------
// 1024 blocks; bh = gid&31 (round-robin = XCD-local), jt longest-first.
// 4 waves/block, wave owns 16 q rows; shared 2-buffer K/V LDS staging with
// counted vmcnt; swapped QK^T; exp2-domain softmax; T13 defer-max.
// T15: PV(t-1) runs at the TOP of iter t from register-resident P/V fragments
// (8 MFMAs issue immediately after the barrier while K ds_reads fly); the
// softmax(t) VALU then overlaps MFMA completion. Final PV peeled after loop.
__global__ __launch_bounds__(256, 4) void attn(
    const unsigned short* __restrict__ Q, const unsigned short* __restrict__ K,
    const unsigned short* __restrict__ VT, unsigned short* __restrict__ O)
{
    __shared__ __align__(16) unsigned short kv_lds[2][2][64 * 64];  // 32 KB
    __shared__ __align__(16) unsigned short plbuf[4][16 * 64];      // 8 KB
    const int tid = threadIdx.x, lane = tid & 63, w = tid >> 6;
    const int g = lane >> 4, c = lane & 15;

    const int gid = blockIdx.x;
    const int bh = gid & 31;
    const int jt = (gid < 512) ? (31 - (gid >> 5)) : ((gid - 512) >> 5);
    const int q0b = jt * 64;
    const int qw0 = q0b + w * 16;              // this wave's first q row

    const unsigned short* Qb = Q  + (size_t)bh * T_LEN * HD_DIM;
    const unsigned short* Kb = K  + (size_t)bh * T_LEN * HD_DIM;
    const unsigned short* Vb = VT + (size_t)bh * HD_DIM * T_LEN;
    unsigned short* pl = plbuf[w];

    // Q fragments (B-operand): lane holds q col (qw0+c), k-slice d = kk*32+g*8
    bf16x8 qf[2];
    #pragma unroll
    for (int kk = 0; kk < 2; ++kk)
        qf[kk] = *(const bf16x8*)(Qb + (size_t)(qw0 + c) * HD_DIM + kk * 32 + g * 8);

    f32x4 acc[4];                    // acc[ni]: row q = g*4+r, col d = ni*16+c
    #pragma unroll
    for (int ni = 0; ni < 4; ++ni) acc[ni] = (f32x4){0.f, 0.f, 0.f, 0.f};
    float m2 = -1e30f, l2 = 0.f;     // per-lane, q = qw0 + c (exp2 domain)

    // register-carried fragments for the deferred PV
    bf16x8 pa_p[2];                  // P(t) A-fragments
    bf16x8 vf_p[8];                  // V(t) fragments: [ni*2 + kk]

    // stage K(64x64) + V^T(64x64); LDS linear, global source pre-swizzled:
    // LDS[row][c16] = G[row][c16 ^ (row&7)]   (16B units)
    auto stage = [&](int buf, int kv0) {
        unsigned short* kb = &kv_lds[buf][0][0];
        unsigned short* vb = &kv_lds[buf][1][0];
        #pragma unroll
        for (int rnd = 0; rnd < 2; ++rnd) {
            const int bch = rnd * 256 + w * 64;
            const int row = (bch >> 3) + (lane >> 3);
            const int sc16 = (lane & 7) ^ (row & 7);
            gload16(Kb + (size_t)(kv0 + row) * HD_DIM + sc16 * 8, kb + bch * 8);
            gload16(Vb + (size_t)row * T_LEN + kv0 + sc16 * 8,   vb + bch * 8);
        }
    };

    const int ntiles = jt + 1;
    stage(0, 0);
    if (ntiles > 1) stage(1, 64);
    int cur = 0;
    #pragma unroll 1
    for (int t = 0; t < ntiles; ++t) {
        const int kv0 = t << 6;
        if (t + 1 < ntiles)
            asm volatile("s_waitcnt vmcnt(4)" ::: "memory");   // tile t landed; t+1 in flight
        else
            asm volatile("s_waitcnt vmcnt(0)" ::: "memory");
        __builtin_amdgcn_s_barrier();
        const unsigned short* kb = &kv_lds[cur][0][0];
        const unsigned short* vb = &kv_lds[cur][1][0];

        // --- PV(t-1): register-resident fragments, issues with zero latency ---
        if (t > 0) {
            #pragma unroll
            for (int ni = 0; ni < 4; ++ni) {
                acc[ni] = __builtin_amdgcn_mfma_f32_16x16x32_bf16(pa_p[0], vf_p[ni * 2 + 0], acc[ni], 0, 0, 0);
                acc[ni] = __builtin_amdgcn_mfma_f32_16x16x32_bf16(pa_p[1], vf_p[ni * 2 + 1], acc[ni], 0, 0, 0);
            }
        }

        // --- S^T = K Q^T (exp2 domain) ---
        f32x4 sf[4];
        #pragma unroll
        for (int st = 0; st < 4; ++st) {
            const int rr = st * 16 + c;
            bf16x8 kf0 = *(const bf16x8*)(kb + rr * 64 + ((g       ^ (c & 7)) * 8));
            bf16x8 kf1 = *(const bf16x8*)(kb + rr * 64 + (((4 + g) ^ (c & 7)) * 8));
            f32x4 s = (f32x4){0.f, 0.f, 0.f, 0.f};
            s = __builtin_amdgcn_mfma_f32_16x16x32_bf16(kf0, qf[0], s, 0, 0, 0);
            s = __builtin_amdgcn_mfma_f32_16x16x32_bf16(kf1, qf[1], s, 0, 0, 0);
            sf[st] = s;
        }
        // causal mask on the diagonal tile only
        if (t == jt) {
            const int qg = qw0 + c;
            #pragma unroll
            for (int st = 0; st < 4; ++st)
                #pragma unroll
                for (int r = 0; r < 4; ++r) {
                    const int kvg = kv0 + st * 16 + g * 4 + r;
                    sf[st][r] = (kvg <= qg) ? sf[st][r] : -1e30f;
                }
        }
        // in-register online softmax (row = q = lane's c), max3-friendly tree
        float ma = fmaxf(fmaxf(sf[0][0], sf[0][1]), sf[0][2]);
        float mb = fmaxf(fmaxf(sf[0][3], sf[1][0]), sf[1][1]);
        float mc = fmaxf(fmaxf(sf[1][2], sf[1][3]), sf[2][0]);
        float md = fmaxf(fmaxf(sf[2][1], sf[2][2]), sf[2][3]);
        float me = fmaxf(fmaxf(sf[3][0], sf[3][1]), sf[3][2]);
        float mx = fmaxf(fmaxf(fmaxf(ma, mb), fmaxf(mc, md)), fmaxf(me, sf[3][3]));
        mx = fmaxf(mx, __shfl_xor(mx, 16));
        mx = fmaxf(mx, __shfl_xor(mx, 32));
        // T13 defer-rescale (exp2 domain: P bounded by 2^8)
        if (__any(mx > m2 + 8.f)) {
            const float mnew = fmaxf(m2, mx);
            const float alpha = __builtin_amdgcn_exp2f(m2 - mnew);
            float ar[4];
            #pragma unroll
            for (int r = 0; r < 4; ++r) ar[r] = __shfl(alpha, g * 4 + r);
            l2 *= alpha;
            #pragma unroll
            for (int ni = 0; ni < 4; ++ni)
                #pragma unroll
                for (int r = 0; r < 4; ++r) acc[ni][r] *= ar[r];
            m2 = mnew;
        }
        float sum = 0.f;
        #pragma unroll
        for (int st = 0; st < 4; ++st)
            #pragma unroll
            for (int r = 0; r < 4; ++r) {
                const float p = __builtin_amdgcn_exp2f(sf[st][r] - m2);
                sf[st][r] = p;
                sum += p;
            }
        sum += __shfl_xor(sum, 16);
        sum += __shfl_xor(sum, 32);
        l2 += sum;
        // pack P (bf16) into pl[q][kv], XOR-swizzled: 4 x ds_write_b64
        #pragma unroll
        for (int st = 0; st < 4; ++st) {
            uint2 pk;
            pk.x = pack2bf(sf[st][0], sf[st][1]);
            pk.y = pack2bf(sf[st][2], sf[st][3]);
            const int idx = (c * 64 + st * 16 + g * 4) ^ ((c & 7) << 3);
            *(uint2*)(pl + idx) = pk;
        }
        asm volatile("" ::: "memory");
        // A-layout P fragments: lane row q = c, kv slice kk*32+g*8
        #pragma unroll
        for (int kk = 0; kk < 2; ++kk) {
            const int ridx = (c * 64 + kk * 32 + g * 8) ^ ((c & 7) << 3);
            pa_p[kk] = *(const bf16x8*)(pl + ridx);
        }
        // V(t) fragments into registers (consumed by PV at iter t+1 / epilogue)
        #pragma unroll
        for (int ni = 0; ni < 4; ++ni) {
            const int rr = ni * 16 + c;
            vf_p[ni * 2 + 0] = *(const bf16x8*)(vb + rr * 64 + ((g       ^ (c & 7)) * 8));
            vf_p[ni * 2 + 1] = *(const bf16x8*)(vb + rr * 64 + (((4 + g) ^ (c & 7)) * 8));
        }
        asm volatile("s_waitcnt lgkmcnt(0)" ::: "memory");
        __builtin_amdgcn_s_barrier();              // all waves done reading buf cur
        if (t + 2 < ntiles) stage(cur, (t + 2) << 6);   // overwrite released buf
        cur ^= 1;
    }

    // peeled final PV(ntiles-1)
    #pragma unroll
    for (int ni = 0; ni < 4; ++ni) {
        acc[ni] = __builtin_amdgcn_mfma_f32_16x16x32_bf16(pa_p[0], vf_p[ni * 2 + 0], acc[ni], 0, 0, 0);
        acc[ni] = __builtin_amdgcn_mfma_f32_16x16x32_bf16(pa_p[1], vf_p[ni * 2 + 1], acc[ni], 0, 0, 0);
    }

    // epilogue: 1/l per q row (l lives at lane c == row)
    const float linv = 1.0f / l2;
    float lr[4];
    #pragma unroll
    for (int r = 0; r < 4; ++r) lr[r] = __shfl(linv, g * 4 + r);
    const int b_ = bh >> 4, h = bh & 15;
    #pragma unroll
    for (int ni = 0; ni < 4; ++ni)
        #pragma unroll
        for (int r = 0; r < 4; ++r) {
            const int q = qw0 + g * 4 + r;
            O[(size_t)(b_ * T_LEN + q) * D_DIM + h * HD_DIM + ni * 16 + c] =
                f2bf(acc[ni][r] * lr[r]);
        }
}

extern "C" void kernel_launch(void* const* d_in, const int* in_sizes, int n_in,
                              void* d_out, int out_size, void* d_ws, size_t ws_size,
                              hipStream_t stream)
{
    const float* x  = (const float*)d_in[0];
    const float* Wq = (const float*)d_in[1];
    const float* bq = (const float*)d_in[2];
    const float* Wk = (const float*)d_in[3];
    const float* bk = (const float*)d_in[4];
    const float* Wv = (const float*)d_in[5];
    const float* bv = (const float*)d_in[6];
    const float* Wo = (const float*)d_in[7];
    const float* bo = (const float*)d_in[8];
    float* out = (float*)d_out;

    char* ws = (char*)d_ws;
    const size_t MB = 1u << 20;
    unsigned short* xb  = (unsigned short*)(ws + 0 * MB);   // 8 MB [4096,1024]
    unsigned short* wqb = (unsigned short*)(ws + 8 * MB);   // 2 MB
    unsigned short* wkb = (unsigned short*)(ws + 10 * MB);  // 2 MB
    unsigned short* wvb = (unsigned short*)(ws + 12 * MB);  // 2 MB
    unsigned short* wob = (unsigned short*)(ws + 14 * MB);  // 2 MB
    unsigned short* qw  = (unsigned short*)(ws + 16 * MB);  // 8 MB [B,H,T,64]
    unsigned short* kw  = (unsigned short*)(ws + 24 * MB);  // 8 MB [B,H,T,64]
    unsigned short* vtw = (unsigned short*)(ws + 32 * MB);  // 8 MB [B,H,64,T]
    unsigned short* ow  = (unsigned short*)(ws + 40 * MB);  // 8 MB [B*T,1024]

    cvt5<<<dim3(1024, 1, 5), dim3(256), 0, stream>>>(
        x, Wq, Wk, Wv, Wo, xb, wqb, wkb, wvb, wob,
        B_NUM * T_LEN * D_DIM, D_DIM * D_DIM, D_DIM * D_DIM, D_DIM * D_DIM, D_DIM * D_DIM);

    gemm_qkv<<<dim3(768), dim3(256), 0, stream>>>(
        xb, wqb, wkb, wvb, bq, bk, bv, qw, kw, vtw);

    attn<<<dim3(1024), dim3(256), 0, stream>>>(qw, kw, vtw, ow);

    gemm_out<<<dim3(256), dim3(256), 0, stream>>>(
        ow, wob, bo, out);
}

// Round 17
// 97.200 us; speedup vs baseline: 1.0276x; 1.0276x over previous
//
#include <hip/hip_runtime.h>
#include <hip/hip_bf16.h>

#define B_NUM 2
#define T_LEN 2048
#define D_DIM 1024
#define H_NUM 16
#define HD_DIM 64

// softmax scale folded into Q projection: 1/sqrt(64) * log2(e)
#define Q_PRESCALE 0.18033688011112042f

using bf16x8 = __attribute__((ext_vector_type(8))) short;
using f32x4  = __attribute__((ext_vector_type(4))) float;
using u16x4  = __attribute__((ext_vector_type(4))) unsigned short;

__device__ __forceinline__ unsigned short f2bf(float f) {
    union { __hip_bfloat16 b; unsigned short u; } v;
    v.b = __float2bfloat16(f);
    return v.u;
}

__device__ __forceinline__ unsigned pack2bf(float a, float b) {
    union { __hip_bfloat162 h; unsigned u; } v;
    v.h = __float22bfloat162_rn(float2{a, b});
    return v.u;
}

__device__ __forceinline__ void gload16(const unsigned short* g, unsigned short* l) {
    __builtin_amdgcn_global_load_lds(
        (const __attribute__((address_space(1))) void*)g,
        (__attribute__((address_space(3))) void*)l, 16, 0, 0);
}

// ---------------- convert fp32 -> bf16 (x + 4 weights), grid-stride ----------------
__global__ __launch_bounds__(256) void cvt5(
    const float* __restrict__ s0, const float* __restrict__ s1, const float* __restrict__ s2,
    const float* __restrict__ s3, const float* __restrict__ s4,
    unsigned short* __restrict__ d0, unsigned short* __restrict__ d1, unsigned short* __restrict__ d2,
    unsigned short* __restrict__ d3, unsigned short* __restrict__ d4,
    int c0, int c1, int c2, int c3, int c4)
{
    const float* src; unsigned short* dst; int cnt;
    switch (blockIdx.z) {
        case 0: src = s0; dst = d0; cnt = c0; break;
        case 1: src = s1; dst = d1; cnt = c1; break;
        case 2: src = s2; dst = d2; cnt = c2; break;
        case 3: src = s3; dst = d3; cnt = c3; break;
        default: src = s4; dst = d4; cnt = c4; break;
    }
    const int stride = gridDim.x * 256 * 4;
    for (int i = (blockIdx.x * 256 + threadIdx.x) * 4; i < cnt; i += stride) {
        float4 v = *(const float4*)(src + i);
        u16x4 o = { f2bf(v.x), f2bf(v.y), f2bf(v.z), f2bf(v.w) };
        *(u16x4*)(dst + i) = o;
    }
}

// ---------- 128x128 tile core: 3-buffer, SINGLE barrier/step, counted vmcnt ----------
// Step t: vmcnt(4) [own tile-t loads landed] ; lgkm(0) [own reads of t-1 done] ;
// barrier [=> ALL waves: tile-t landed AND reads of buf (t-1)%3 done] ;
// stage(t+2) into buf (t+2)%3 == (t-1)%3 [safe: reads certified] ; ds_read(t) ; MFMA.
// One barrier per K-step (was two); same 48 KB LDS, 3 blocks/CU.
__device__ __forceinline__ void tile128(
    const unsigned short* __restrict__ A, const unsigned short* __restrict__ Bm,
    int m0, int n0, int K, unsigned short* lds, f32x4 acc[4][4])
{
    const int tid  = threadIdx.x;
    const int lane = tid & 63, w = tid >> 6;
    const int g = lane >> 4, c = lane & 15;
    const int wr = w >> 1, wc = w & 1;
    const int srow = lane >> 2;                 // row within 16-row staging chunk
    const int sch  = lane & 3;                  // 16B chunk within the 64B row
    const int scsw = sch ^ ((srow >> 1) & 3);   // swizzled source chunk
    const int chunk = w * 2;                    // wave stages chunks {chunk, chunk+1}
    const int row0 = chunk * 16 + srow;
    const int row1 = row0 + 16;
    const int rsw = (c >> 1) & 3;               // read-side XOR (row bits 1..2)

    #pragma unroll
    for (int mi = 0; mi < 4; ++mi)
        #pragma unroll
        for (int ni = 0; ni < 4; ++ni)
            acc[mi][ni] = (f32x4){0.f, 0.f, 0.f, 0.f};

    const unsigned short* gA0 = A  + (size_t)(m0 + row0) * K + scsw * 8;
    const unsigned short* gA1 = A  + (size_t)(m0 + row1) * K + scsw * 8;
    const unsigned short* gB0 = Bm + (size_t)(n0 + row0) * K + scsw * 8;
    const unsigned short* gB1 = Bm + (size_t)(n0 + row1) * K + scsw * 8;

    auto stage = [&](int buf, int k0) {
        unsigned short* bA = lds + buf * 8192;
        unsigned short* bB = bA + 4096;
        gload16(gA0 + k0, bA + chunk * 512);
        gload16(gA1 + k0, bA + (chunk + 1) * 512);
        gload16(gB0 + k0, bB + chunk * 512);
        gload16(gB1 + k0, bB + (chunk + 1) * 512);
    };

    const int nsteps = K / 32;
    stage(0, 0);
    stage(1, 32);
    int buf = 0;
    #pragma unroll 1
    for (int t = 0; t < nsteps; ++t) {
        if (t + 1 < nsteps)
            asm volatile("s_waitcnt vmcnt(4)" ::: "memory");   // own tile-t loads landed
        else
            asm volatile("s_waitcnt vmcnt(0)" ::: "memory");
        asm volatile("s_waitcnt lgkmcnt(0)" ::: "memory");     // own reads of t-1 done
        __builtin_amdgcn_s_barrier();                          // all waves: both certified
        if (t + 2 < nsteps) {
            int nb = buf + 2; if (nb >= 3) nb -= 3;
            stage(nb, (t + 2) * 32);                           // overwrites buf (t-1)%3: safe
        }
        const unsigned short* bA = lds + buf * 8192;
        const unsigned short* bB = bA + 4096;
        bf16x8 af[4], bfr[4];
        #pragma unroll
        for (int mi = 0; mi < 4; ++mi)
            af[mi] = *(const bf16x8*)(bA + (wr * 64 + mi * 16 + c) * 32 + (g ^ rsw) * 8);
        #pragma unroll
        for (int ni = 0; ni < 4; ++ni)
            bfr[ni] = *(const bf16x8*)(bB + (wc * 64 + ni * 16 + c) * 32 + (g ^ rsw) * 8);
        #pragma unroll
        for (int mi = 0; mi < 4; ++mi)
            #pragma unroll
            for (int ni = 0; ni < 4; ++ni)
                acc[mi][ni] = __builtin_amdgcn_mfma_f32_16x16x32_bf16(af[mi], bfr[ni], acc[mi][ni], 0, 0, 0);
        ++buf; if (buf == 3) buf = 0;
    }
}

// Fused QKV projection, 1D grid of 768. XCD factorization 8mt x 12rr.
// Q output pre-scaled by Q_PRESCALE (softmax scale folded in, exp2 domain).
__global__ __launch_bounds__(256) void gemm_qkv(
    const unsigned short* __restrict__ X,
    const unsigned short* __restrict__ Wq, const unsigned short* __restrict__ Wk,
    const unsigned short* __restrict__ Wv,
    const float* __restrict__ bq, const float* __restrict__ bk, const float* __restrict__ bv,
    unsigned short* __restrict__ Oq, unsigned short* __restrict__ Ok, unsigned short* __restrict__ OvT)
{
    __shared__ __align__(16) unsigned short lds[3 * 8192];
    const int xcd = blockIdx.x & 7;
    const int s   = blockIdx.x >> 3;            // 0..95
    const int mt  = (xcd >> 1) * 8 + s / 12;
    const int rr  = (xcd & 1) * 12 + s % 12;
    const int z   = rr >> 3;
    const int nt  = rr & 7;

    const int lane = threadIdx.x & 63, w = threadIdx.x >> 6;
    const int g = lane >> 4, c = lane & 15;
    const int wr = w >> 1, wc = w & 1;
    f32x4 acc[4][4];

    if (z < 2) {
        const unsigned short* W = z ? Wk : Wq;
        const float* bias       = z ? bk : bq;
        unsigned short* Ob      = z ? Ok : Oq;
        const float oscale      = z ? 1.0f : Q_PRESCALE;
        const int m0 = mt * 128, n0 = nt * 128;
        tile128(X, W, m0, n0, D_DIM, lds, acc);
        #pragma unroll
        for (int mi = 0; mi < 4; ++mi) {
            #pragma unroll
            for (int ni = 0; ni < 4; ++ni) {
                const int col = n0 + wc * 64 + ni * 16 + c;
                const int h = col >> 6, hd = col & 63;
                const float bb = bias[col];
                #pragma unroll
                for (int r = 0; r < 4; ++r) {
                    const int row = m0 + wr * 64 + mi * 16 + g * 4 + r;
                    const int b_ = row >> 11, t = row & (T_LEN - 1);
                    Ob[((size_t)((b_ * H_NUM + h) * T_LEN + t)) * HD_DIM + hd] =
                        f2bf((acc[mi][ni][r] + bb) * oscale);
                }
            }
        }
    } else {
        // V^T: C'[f][j] = sum_k Wv[f][k] * X[j][k]
        const int m0 = nt * 128, n0 = mt * 128;
        tile128(Wv, X, m0, n0, D_DIM, lds, acc);
        #pragma unroll
        for (int mi = 0; mi < 4; ++mi) {
            #pragma unroll
            for (int ni = 0; ni < 4; ++ni) {
                const int j = n0 + wc * 64 + ni * 16 + c;
                const int b_ = j >> 11, t = j & (T_LEN - 1);
                #pragma unroll
                for (int r = 0; r < 4; ++r) {
                    const int f = m0 + wr * 64 + mi * 16 + g * 4 + r;
                    OvT[(size_t)(b_ * D_DIM + f) * T_LEN + t] = f2bf(acc[mi][ni][r] + bv[f]);
                }
            }
        }
    }
}

// Output projection: fp32 result to d_out. 256 blocks, XCD-chunked.
__global__ __launch_bounds__(256) void gemm_out(
    const unsigned short* __restrict__ A, const unsigned short* __restrict__ W,
    const float* __restrict__ bias, float* __restrict__ Out)
{
    __shared__ __align__(16) unsigned short lds[3 * 8192];
    const int bsw = (blockIdx.x & 7) * 32 + (blockIdx.x >> 3);
    const int mt = bsw >> 3, nt = bsw & 7;
    const int lane = threadIdx.x & 63, w = threadIdx.x >> 6;
    const int g = lane >> 4, c = lane & 15;
    const int m0 = mt * 128, n0 = nt * 128;
    f32x4 acc[4][4];
    tile128(A, W, m0, n0, D_DIM, lds, acc);
    const int wr = w >> 1, wc = w & 1;
    #pragma unroll
    for (int mi = 0; mi < 4; ++mi) {
        #pragma unroll
        for (int ni = 0; ni < 4; ++ni) {
            const int col = n0 + wc * 64 + ni * 16 + c;
            const float bb = bias[col];
            #pragma unroll
            for (int r = 0; r < 4; ++r) {
                const int row = m0 + wr * 64 + mi * 16 + g * 4 + r;
                Out[(size_t)row * D_DIM + col] = acc[mi][ni][r] + bb;
            }
        }
    }
}

// ---------------- flash attention v7 (r10/r15 verbatim — best measured: 40.3 us) ----------------
// 1024 blocks; bh = gid&31 (round-robin = XCD-local), jt longest-first.
// 4 waves/block, wave owns 16 q rows; shared 2-buffer K/V LDS staging with
// counted vmcnt (never drains to 0 mid-loop); swapped QK^T; Q pre-scaled by
// 0.125*log2e so softmax is pure exp2; T13 defer-max. No setprio (r13: -10%);
// no deferred-PV (r16: null).
__global__ __launch_bounds__(256, 4) void attn(
    const unsigned short* __restrict__ Q, const unsigned short* __restrict__ K,
    const unsigned short* __restrict__ VT, unsigned short* __restrict__ O)
{
    __shared__ __align__(16) unsigned short kv_lds[2][2][64 * 64];  // 32 KB
    __shared__ __align__(16) unsigned short plbuf[4][16 * 64];      // 8 KB
    const int tid = threadIdx.x, lane = tid & 63, w = tid >> 6;
    const int g = lane >> 4, c = lane & 15;

    const int gid = blockIdx.x;
    const int bh = gid & 31;
    const int jt = (gid < 512) ? (31 - (gid >> 5)) : ((gid - 512) >> 5);
    const int q0b = jt * 64;
    const int qw0 = q0b + w * 16;              // this wave's first q row

    const unsigned short* Qb = Q  + (size_t)bh * T_LEN * HD_DIM;
    const unsigned short* Kb = K  + (size_t)bh * T_LEN * HD_DIM;
    const unsigned short* Vb = VT + (size_t)bh * HD_DIM * T_LEN;
    unsigned short* pl = plbuf[w];

    // Q fragments (B-operand): lane holds q col (qw0+c), k-slice d = kk*32+g*8
    bf16x8 qf[2];
    #pragma unroll
    for (int kk = 0; kk < 2; ++kk)
        qf[kk] = *(const bf16x8*)(Qb + (size_t)(qw0 + c) * HD_DIM + kk * 32 + g * 8);

    f32x4 acc[4];                    // acc[ni]: row q = g*4+r, col d = ni*16+c
    #pragma unroll
    for (int ni = 0; ni < 4; ++ni) acc[ni] = (f32x4){0.f, 0.f, 0.f, 0.f};
    float m2 = -1e30f, l2 = 0.f;     // per-lane, q = qw0 + c (exp2 domain)

    // stage K(64x64) + V^T(64x64); LDS linear, global source pre-swizzled:
    // LDS[row][c16] = G[row][c16 ^ (row&7)]   (16B units)
    auto stage = [&](int buf, int kv0) {
        unsigned short* kb = &kv_lds[buf][0][0];
        unsigned short* vb = &kv_lds[buf][1][0];
        #pragma unroll
        for (int rnd = 0; rnd < 2; ++rnd) {
            const int bch = rnd * 256 + w * 64;
            const int row = (bch >> 3) + (lane >> 3);
            const int sc16 = (lane & 7) ^ (row & 7);
            gload16(Kb + (size_t)(kv0 + row) * HD_DIM + sc16 * 8, kb + bch * 8);
            gload16(Vb + (size_t)row * T_LEN + kv0 + sc16 * 8,   vb + bch * 8);
        }
    };

    const int ntiles = jt + 1;
    stage(0, 0);
    if (ntiles > 1) stage(1, 64);
    int cur = 0;
    #pragma unroll 1
    for (int t = 0; t < ntiles; ++t) {
        const int kv0 = t << 6;
        if (t + 1 < ntiles)
            asm volatile("s_waitcnt vmcnt(4)" ::: "memory");   // tile t landed; t+1 in flight
        else
            asm volatile("s_waitcnt vmcnt(0)" ::: "memory");
        __builtin_amdgcn_s_barrier();
        const unsigned short* kb = &kv_lds[cur][0][0];
        const unsigned short* vb = &kv_lds[cur][1][0];

        // S^T = K Q^T (already in exp2 domain; no scale needed)
        f32x4 sf[4];
        #pragma unroll
        for (int st = 0; st < 4; ++st) {
            const int rr = st * 16 + c;
            bf16x8 kf0 = *(const bf16x8*)(kb + rr * 64 + ((g       ^ (c & 7)) * 8));
            bf16x8 kf1 = *(const bf16x8*)(kb + rr * 64 + (((4 + g) ^ (c & 7)) * 8));
            f32x4 s = (f32x4){0.f, 0.f, 0.f, 0.f};
            s = __builtin_amdgcn_mfma_f32_16x16x32_bf16(kf0, qf[0], s, 0, 0, 0);
            s = __builtin_amdgcn_mfma_f32_16x16x32_bf16(kf1, qf[1], s, 0, 0, 0);
            sf[st] = s;
        }
        // causal mask on the diagonal tile only (no scale mul anywhere)
        if (t == jt) {
            const int qg = qw0 + c;
            #pragma unroll
            for (int st = 0; st < 4; ++st)
                #pragma unroll
                for (int r = 0; r < 4; ++r) {
                    const int kvg = kv0 + st * 16 + g * 4 + r;
                    sf[st][r] = (kvg <= qg) ? sf[st][r] : -1e30f;
                }
        }
        // in-register online softmax (row = q = lane's c), max3-friendly tree
        float ma = fmaxf(fmaxf(sf[0][0], sf[0][1]), sf[0][2]);
        float mb = fmaxf(fmaxf(sf[0][3], sf[1][0]), sf[1][1]);
        float mc = fmaxf(fmaxf(sf[1][2], sf[1][3]), sf[2][0]);
        float md = fmaxf(fmaxf(sf[2][1], sf[2][2]), sf[2][3]);
        float me = fmaxf(fmaxf(sf[3][0], sf[3][1]), sf[3][2]);
        float mx = fmaxf(fmaxf(fmaxf(ma, mb), fmaxf(mc, md)), fmaxf(me, sf[3][3]));
        mx = fmaxf(mx, __shfl_xor(mx, 16));
        mx = fmaxf(mx, __shfl_xor(mx, 32));
        // T13 defer-rescale (exp2 domain: P bounded by 2^8)
        if (__any(mx > m2 + 8.f)) {
            const float mnew = fmaxf(m2, mx);
            const float alpha = __builtin_amdgcn_exp2f(m2 - mnew);
            float ar[4];
            #pragma unroll
            for (int r = 0; r < 4; ++r) ar[r] = __shfl(alpha, g * 4 + r);
            l2 *= alpha;
            #pragma unroll
            for (int ni = 0; ni < 4; ++ni)
                #pragma unroll
                for (int r = 0; r < 4; ++r) acc[ni][r] *= ar[r];
            m2 = mnew;
        }
        float sum = 0.f;
        #pragma unroll
        for (int st = 0; st < 4; ++st)
            #pragma unroll
            for (int r = 0; r < 4; ++r) {
                const float p = __builtin_amdgcn_exp2f(sf[st][r] - m2);
                sf[st][r] = p;
                sum += p;
            }
        sum += __shfl_xor(sum, 16);
        sum += __shfl_xor(sum, 32);
        l2 += sum;
        // pack P (bf16) into pl[q][kv], XOR-swizzled: 4 x ds_write_b64
        #pragma unroll
        for (int st = 0; st < 4; ++st) {
            uint2 pk;
            pk.x = pack2bf(sf[st][0], sf[st][1]);
            pk.y = pack2bf(sf[st][2], sf[st][3]);
            const int idx = (c * 64 + st * 16 + g * 4) ^ ((c & 7) << 3);
            *(uint2*)(pl + idx) = pk;
        }
        asm volatile("" ::: "memory");
        // A-layout P fragments: lane row q = c, kv slice kk*32+g*8
        bf16x8 pa[2];
        #pragma unroll
        for (int kk = 0; kk < 2; ++kk) {
            const int ridx = (c * 64 + kk * 32 + g * 8) ^ ((c & 7) << 3);
            pa[kk] = *(const bf16x8*)(pl + ridx);
        }
        // PV: acc(16x64) += P(16x64) V(64x64); V^T rows from LDS, swizzled read
        #pragma unroll
        for (int ni = 0; ni < 4; ++ni) {
            const int rr = ni * 16 + c;
            bf16x8 vf0 = *(const bf16x8*)(vb + rr * 64 + ((g       ^ (c & 7)) * 8));
            bf16x8 vf1 = *(const bf16x8*)(vb + rr * 64 + (((4 + g) ^ (c & 7)) * 8));
            acc[ni] = __builtin_amdgcn_mfma_f32_16x16x32_bf16(pa[0], vf0, acc[ni], 0, 0, 0);
            acc[ni] = __builtin_amdgcn_mfma_f32_16x16x32_bf16(pa[1], vf1, acc[ni], 0, 0, 0);
        }
        asm volatile("s_waitcnt lgkmcnt(0)" ::: "memory");
        __builtin_amdgcn_s_barrier();              // all waves done reading buf cur
        if (t + 2 < ntiles) stage(cur, (t + 2) << 6);   // overwrite released buf
        cur ^= 1;
    }

    // epilogue: 1/l per q row (l lives at lane c == row)
    const float linv = 1.0f / l2;
    float lr[4];
    #pragma unroll
    for (int r = 0; r < 4; ++r) lr[r] = __shfl(linv, g * 4 + r);
    const int b_ = bh >> 4, h = bh & 15;
    #pragma unroll
    for (int ni = 0; ni < 4; ++ni)
        #pragma unroll
        for (int r = 0; r < 4; ++r) {
            const int q = qw0 + g * 4 + r;
            O[(size_t)(b_ * T_LEN + q) * D_DIM + h * HD_DIM + ni * 16 + c] =
                f2bf(acc[ni][r] * lr[r]);
        }
}

extern "C" void kernel_launch(void* const* d_in, const int* in_sizes, int n_in,
                              void* d_out, int out_size, void* d_ws, size_t ws_size,
                              hipStream_t stream)
{
    const float* x  = (const float*)d_in[0];
    const float* Wq = (const float*)d_in[1];
    const float* bq = (const float*)d_in[2];
    const float* Wk = (const float*)d_in[3];
    const float* bk = (const float*)d_in[4];
    const float* Wv = (const float*)d_in[5];
    const float* bv = (const float*)d_in[6];
    const float* Wo = (const float*)d_in[7];
    const float* bo = (const float*)d_in[8];
    float* out = (float*)d_out;

    char* ws = (char*)d_ws;
    const size_t MB = 1u << 20;
    unsigned short* xb  = (unsigned short*)(ws + 0 * MB);   // 8 MB [4096,1024]
    unsigned short* wqb = (unsigned short*)(ws + 8 * MB);   // 2 MB
    unsigned short* wkb = (unsigned short*)(ws + 10 * MB);  // 2 MB
    unsigned short* wvb = (unsigned short*)(ws + 12 * MB);  // 2 MB
    unsigned short* wob = (unsigned short*)(ws + 14 * MB);  // 2 MB
    unsigned short* qw  = (unsigned short*)(ws + 16 * MB);  // 8 MB [B,H,T,64]
    unsigned short* kw  = (unsigned short*)(ws + 24 * MB);  // 8 MB [B,H,T,64]
    unsigned short* vtw = (unsigned short*)(ws + 32 * MB);  // 8 MB [B,H,64,T]
    unsigned short* ow  = (unsigned short*)(ws + 40 * MB);  // 8 MB [B*T,1024]

    cvt5<<<dim3(1024, 1, 5), dim3(256), 0, stream>>>(
        x, Wq, Wk, Wv, Wo, xb, wqb, wkb, wvb, wob,
        B_NUM * T_LEN * D_DIM, D_DIM * D_DIM, D_DIM * D_DIM, D_DIM * D_DIM, D_DIM * D_DIM);

    gemm_qkv<<<dim3(768), dim3(256), 0, stream>>>(
        xb, wqb, wkb, wvb, bq, bk, bv, qw, kw, vtw);

    attn<<<dim3(1024), dim3(256), 0, stream>>>(qw, kw, vtw, ow);

    gemm_out<<<dim3(256), dim3(256), 0, stream>>>(
        ow, wob, bo, out);
}